// Round 6
// baseline (133.549 us; speedup 1.0000x reference)
//
#include <hip/hip_runtime.h>
#include <float.h>

// VQ-VAE vector quantizer forward, MI355X — bf16 MFMA with exact 3-way split.
// x: [B=32, C=64, H=64, W=64] fp32; emb: [K=512, D=64] fp32.
// out flat (b, h*w, c): out[g*64 + c] = emb[argmin_k ||x_g - emb_k||^2][c].
//
// R13: 32x32x16 MFMA. R9-R12 established: ~55us / MfmaUtil ~38% is invariant
// to LDS conflicts, occupancy (2->4 waves: +10%), prefetch depth, and B-path
// (L2 stream vs LDS staged). Remaining suspect: per-instruction overhead —
// 12288 MFMA instr/CU at 16x16x32. R13 halves that (6144 @ 32x32x16) and
// gains the shape's +20% FLOP/cy (4060 vs 3378; floor 24.8 -> 20.7 us).
// Wave owns M=32 pos; tile = 32 codes x K=64 (4 chunks of 16) = 24 MFMA;
// 16 tiles, 16 barriers (was 32). B-frags read per e-level group (only 4
// live -> ~124 VGPR, 4 blocks/CU). LDS dbuf 2x12KB, 3 global_load_lds per
// wave per tile, drained after a full ~3.1K-cy compute window. Prep rewritten
// for 32x32 layout with ushort8 stores (prep ~6us -> ~3us of each iter).
// Same exact 3-way split / 6 classes / fp32 accum; K=16 chunking shifts
// rounding ~1e-7 (<< the ~1e-5 fp32 noise vs reference).
//
// Layouts: 16x16 verified (m89/m91); 32x32 C/D verified (m74/m101):
// col=lane&31, row=(r&3)+8*(r>>2)+4*(lane>>5); A/B: [m|n=lane&31]
// [k=(lane>>5)*8+j] per 16-chunk.

typedef __attribute__((ext_vector_type(8)))  short          short8;
typedef __attribute__((ext_vector_type(8)))  unsigned short ush8;
typedef __attribute__((ext_vector_type(4)))  float          floatx4;
typedef __attribute__((ext_vector_type(16))) float          floatx16;

#define HWD 4096
#define CD  64
#define KD  512
#define PT  128    // positions per block
#define KT  128    // fallback path: emb rows per nt
#define ESR 72     // fallback LDS row stride

// ws layout: bs = 16 tiles x 12288 B ([lvl][chunk][lane][8] bf16 frags for
// 32 codes x 64 dims x 3 levels) = 196608 B; esq = 512 floats at 196608.
#define TILE_B    12288
#define TILE_USH  6144
#define BS_BYTES  (16 * TILE_B)                            // 196608
#define ESQ_OFF   BS_BYTES
#define WS_NEEDED (ESQ_OFF + 512 * (int)sizeof(float))     // 198656

// round-to-nearest-even fp32 -> bf16 (bit-level; inputs are finite)
__device__ inline unsigned short bf16_rne(float v) {
    unsigned int u = __builtin_bit_cast(unsigned int, v);
    u += 0x7fffu + ((u >> 16) & 1u);
    return (unsigned short)(u >> 16);
}
__device__ inline float bf16_val(unsigned short h) {
    return __builtin_bit_cast(float, (unsigned int)h << 16);
}
// exact 3-way split: v = h + m + l + eps, |eps| <= 2^-27 |v|
__device__ inline void split3(float v, unsigned short& h, unsigned short& m,
                              unsigned short& l) {
    h = bf16_rne(v);
    float r1 = v - bf16_val(h);     // exact in fp32
    m = bf16_rne(r1);
    float r2 = r1 - bf16_val(m);    // exact in fp32
    l = bf16_rne(r2);
}

#define MFMA16(A, B, C) __builtin_amdgcn_mfma_f32_16x16x32_bf16((A), (B), (C), 0, 0, 0)
#define MFMA32(A, B, C) __builtin_amdgcn_mfma_f32_32x32x16_bf16((A), (B), (C), 0, 0, 0)

// async global -> LDS, 16 B per lane; LDS dest = wave-uniform base + lane*16
__device__ inline void gload_lds16(const void* g, void* l) {
    __builtin_amdgcn_global_load_lds(
        (const __attribute__((address_space(1))) void*)g,
        (__attribute__((address_space(3))) void*)l, 16, 0, 0);
}

// ---- prep: split emb into 32x32 B-fragment layout + pre-summed |e|^2 ----
// thread t (0..1023): k = t>>1, half = t&1 handles c in [half*32, half*32+32).
// Same value order / fmaf chain / split3 as R7 -> bit-identical esq.
// Frag f = lvl*4 + (c>>4), 1024 B each; within frag: lane = (k&31) +
// 32*((c>>3)&1), elem j = c&7.  Tile = 32 codes (k>>5).
__global__ void vq_prep32(const float* __restrict__ emb,
                          unsigned short* __restrict__ bs,
                          float* __restrict__ esq) {
    const int t    = blockIdx.x * blockDim.x + threadIdx.x;  // 0..1023
    const int k    = t >> 1;
    const int half = t & 1;
    const float* eg = emb + (size_t)k * CD + half * 32;
    unsigned short* tile = bs + (size_t)(k >> 5) * TILE_USH;

    ush8 hv[4], mv[4], lv[4];     // 4 runs of 8 consecutive c
    float s = 0.f;
    #pragma unroll
    for (int q = 0; q < 8; ++q) {
        float4 ev = *(const float4*)(eg + q * 4);
        float vv[4] = {ev.x, ev.y, ev.z, ev.w};
        #pragma unroll
        for (int i = 0; i < 4; ++i) {
            s = fmaf(vv[i], vv[i], s);
            unsigned short h, m, l;
            split3(vv[i], h, m, l);
            const int cl  = q * 4 + i;      // 0..31 (compile-time)
            const int run = cl >> 3;
            const int jj  = cl & 7;
            hv[run][jj] = h; mv[run][jj] = m; lv[run][jj] = l;
        }
    }
    #pragma unroll
    for (int run = 0; run < 4; ++run) {
        const int c0    = half * 32 + run * 8;
        const int chunk = c0 >> 4;
        const int lane_ = (k & 31) + 32 * ((c0 >> 3) & 1);
        unsigned short* p0 = tile + (0 * 4 + chunk) * 512 + lane_ * 8;
        unsigned short* p1 = tile + (1 * 4 + chunk) * 512 + lane_ * 8;
        unsigned short* p2 = tile + (2 * 4 + chunk) * 512 + lane_ * 8;
        *(ush8*)p0 = hv[run];
        *(ush8*)p1 = mv[run];
        *(ush8*)p2 = lv[run];
    }
    // lanes 2k, 2k+1 hold the two half-partials of code k
    float o = __shfl_xor(s, 1, 64);
    if (half == 0) esq[k] = s + o;    // == R7's esq_p[2k] + esq_p[2k+1]
}

// ---- main kernel: 32x32x16 MFMA, LDS dbuf, 16 tiles of 32 codes ----
__launch_bounds__(256, 4)
__global__ void vq_mfma32_kernel(const float* __restrict__ x,
                                 const unsigned short* __restrict__ bs,
                                 const float* __restrict__ esq,
                                 const float* __restrict__ emb,
                                 float* __restrict__ out) {
    const int tid  = threadIdx.x;
    const int lane = tid & 63;
    const int wv   = __builtin_amdgcn_readfirstlane(tid >> 6);  // 0..3
    const int n32  = lane & 31;   // m (pos) for A, n (code) for B, col for D
    const int hi   = lane >> 5;   // k-half for A/B; row offset for D

    const int g0 = blockIdx.x << 7;   // 128 positions per block
    const int b  = g0 >> 12;          // 128 | 4096: no b straddle
    const int n0 = g0 & 4095;

    __shared__ unsigned short lds_b[2][TILE_USH];   // 2 x 12 KB
    __shared__ int bk_s[PT];

    const char* bsb = (const char*)bs;
    char* l0 = (char*)&lds_b[0][0];
    char* l1 = (char*)&lds_b[1][0];

    // ---- stage tile 0 first; latency hides under the split3 prologue ----
    // 12 frag-chunks of 1024 B; wave w stages f = w, w+4, w+8
    #pragma unroll
    for (int s = 0; s < 3; ++s)
        gload_lds16(bsb + (wv + 4 * s) * 1024 + lane * 16,
                    l0 + (wv + 4 * s) * 1024);

    // ---- A fragments: pos = g0 + wv*32 + n32; c = chunk*16 + hi*8 + j ----
    short8 ah[4], am[4], al[4];
    {
        const float* xb = x + (size_t)b * (CD * HWD) + n0 + wv * 32 + n32;
        #pragma unroll
        for (int chunk = 0; chunk < 4; ++chunk)
            #pragma unroll
            for (int j = 0; j < 8; ++j) {
                float v = xb[(size_t)(chunk * 16 + hi * 8 + j) * HWD];
                unsigned short h, m, l;
                split3(v, h, m, l);
                ah[chunk][j] = (short)h;
                am[chunk][j] = (short)m;
                al[chunk][j] = (short)l;
            }
    }

    float bestd[16]; int bestk[16];
    #pragma unroll
    for (int i = 0; i < 16; ++i) { bestd[i] = FLT_MAX; bestk[i] = 0; }

    __syncthreads();   // tile 0 resident

    // Per tile: 24 MFMAs, product classes small->large, B read per e-level:
    // h*l | m*m, h*m | l*h, m*h, h*h   (each class = 4 chained k-chunks)
    #define COMPUTE_TILE(LB, T)                                               \
    {                                                                         \
        const float eqv = esq[(T) * 32 + n32];                                \
        floatx16 acc;                                                         \
        _Pragma("unroll")                                                     \
        for (int r = 0; r < 16; ++r) acc[r] = 0.f;                            \
        short8 b0, b1, b2, b3;                                                \
        /* e_l: frags 8..11 */                                                \
        b0 = *(const short8*)((LB) +  8 * 1024 + lane * 16);                  \
        b1 = *(const short8*)((LB) +  9 * 1024 + lane * 16);                  \
        b2 = *(const short8*)((LB) + 10 * 1024 + lane * 16);                  \
        b3 = *(const short8*)((LB) + 11 * 1024 + lane * 16);                  \
        acc = MFMA32(ah[0], b0, acc); acc = MFMA32(ah[1], b1, acc);           \
        acc = MFMA32(ah[2], b2, acc); acc = MFMA32(ah[3], b3, acc);           \
        /* e_m: frags 4..7 */                                                 \
        b0 = *(const short8*)((LB) + 4 * 1024 + lane * 16);                   \
        b1 = *(const short8*)((LB) + 5 * 1024 + lane * 16);                   \
        b2 = *(const short8*)((LB) + 6 * 1024 + lane * 16);                   \
        b3 = *(const short8*)((LB) + 7 * 1024 + lane * 16);                   \
        acc = MFMA32(am[0], b0, acc); acc = MFMA32(am[1], b1, acc);           \
        acc = MFMA32(am[2], b2, acc); acc = MFMA32(am[3], b3, acc);           \
        acc = MFMA32(ah[0], b0, acc); acc = MFMA32(ah[1], b1, acc);           \
        acc = MFMA32(ah[2], b2, acc); acc = MFMA32(ah[3], b3, acc);           \
        /* e_h: frags 0..3 */                                                 \
        b0 = *(const short8*)((LB) + 0 * 1024 + lane * 16);                   \
        b1 = *(const short8*)((LB) + 1 * 1024 + lane * 16);                   \
        b2 = *(const short8*)((LB) + 2 * 1024 + lane * 16);                   \
        b3 = *(const short8*)((LB) + 3 * 1024 + lane * 16);                   \
        acc = MFMA32(al[0], b0, acc); acc = MFMA32(al[1], b1, acc);           \
        acc = MFMA32(al[2], b2, acc); acc = MFMA32(al[3], b3, acc);           \
        acc = MFMA32(am[0], b0, acc); acc = MFMA32(am[1], b1, acc);           \
        acc = MFMA32(am[2], b2, acc); acc = MFMA32(am[3], b3, acc);           \
        acc = MFMA32(ah[0], b0, acc); acc = MFMA32(ah[1], b1, acc);           \
        acc = MFMA32(ah[2], b2, acc); acc = MFMA32(ah[3], b3, acc);           \
        /* distances + running argmin (k ascending: strict <) */              \
        const int kv = (T) * 32 + n32;                                        \
        _Pragma("unroll")                                                     \
        for (int r = 0; r < 16; ++r) {                                        \
            float d = fmaf(-2.f, acc[r], eqv);                                \
            if (d < bestd[r]) { bestd[r] = d; bestk[r] = kv; }                \
        }                                                                     \
    }

    // ---- main loop: 8 iters x 2 tiles; dbuf static indexing ----
    #pragma unroll 1
    for (int it = 0; it < 8; ++it) {
        {   // tile 2it from l0; stage 2it+1 -> l1
            const char* nb = bsb + (size_t)(2 * it + 1) * TILE_B;
            #pragma unroll
            for (int s = 0; s < 3; ++s)
                gload_lds16(nb + (wv + 4 * s) * 1024 + lane * 16,
                            l1 + (wv + 4 * s) * 1024);
            COMPUTE_TILE(l0, 2 * it)
            __syncthreads();
        }
        {   // tile 2it+1 from l1; stage 2it+2 -> l0 (skip on last)
            if (it < 7) {
                const char* nb = bsb + (size_t)(2 * it + 2) * TILE_B;
                #pragma unroll
                for (int s = 0; s < 3; ++s)
                    gload_lds16(nb + (wv + 4 * s) * 1024 + lane * 16,
                                l0 + (wv + 4 * s) * 1024);
            }
            COMPUTE_TILE(l1, 2 * it + 1)
            __syncthreads();
        }
    }
    #undef COMPUTE_TILE

    // ---- cross-lane argmin over the 32 code-columns (lane bits 0..4) ----
    #pragma unroll
    for (int msk = 1; msk <= 16; msk <<= 1)
        #pragma unroll
        for (int i = 0; i < 16; ++i) {
            float od = __shfl_xor(bestd[i], msk, 64);
            int   ok = __shfl_xor(bestk[i], msk, 64);
            bool take = (od < bestd[i]) || (od == bestd[i] && ok < bestk[i]);
            if (take) { bestd[i] = od; bestk[i] = ok; }
        }
    // D row(r) = (r&3) + 8*(r>>2) + 4*hi -> pos = wv*32 + row
    if (n32 == 0) {
        #pragma unroll
        for (int r = 0; r < 16; ++r)
            bk_s[wv * 32 + (r & 3) + 8 * (r >> 2) + 4 * hi] = bestk[r];
    }
    __syncthreads();

    // ---- gather epilogue: wave-uniform rows, 256-B coalesced, batched ----
    const size_t ob = (size_t)g0 * CD;
    for (int it = 0; it < 8; ++it) {
        float v[4]; int pp[4];
        #pragma unroll
        for (int j = 0; j < 4; ++j) {
            int p = (it * 4 + j) * 4 + wv;
            pp[j] = p;
            v[j]  = emb[bk_s[p] * CD + lane];   // L2-hot fp32 row
        }
        #pragma unroll
        for (int j = 0; j < 4; ++j)
            out[ob + (size_t)pp[j] * CD + lane] = v[j];
    }
}

// ---- fallback (no workspace): verbatim R7 kernel, 123.7 us known-good ----
__launch_bounds__(256, 2)
__global__ void vq_mfma_fb(const float* __restrict__ x,
                           const float* __restrict__ emb,
                           float* __restrict__ out) {
    const int tid  = threadIdx.x;
    const int lane = tid & 63;
    const int wv   = __builtin_amdgcn_readfirstlane(tid >> 6);  // 0..3
    const int n16  = lane & 15;
    const int quad = lane >> 4;

    const int g0 = blockIdx.x << 8;
    const int b  = g0 >> 12;
    const int n0 = g0 & 4095;

    __shared__ unsigned short es_h[KT][ESR];
    __shared__ unsigned short es_m[KT][ESR];
    __shared__ unsigned short es_l[KT][ESR];
    __shared__ float esq_p[2 * KT];
    __shared__ int   bk_s[256];

    short8 ah[4][2], am[4][2], al[4][2];
    {
        const float* xb = x + (size_t)b * (CD * HWD) + n0 + wv * 64 + n16;
        #pragma unroll
        for (int mt = 0; mt < 4; ++mt)
            #pragma unroll
            for (int ch = 0; ch < 2; ++ch) {
                #pragma unroll
                for (int j = 0; j < 8; ++j) {
                    float v = xb[(size_t)(ch * 32 + quad * 8 + j) * HWD + mt * 16];
                    unsigned short h, m, l;
                    split3(v, h, m, l);
                    ah[mt][ch][j] = (short)h;
                    am[mt][ch][j] = (short)m;
                    al[mt][ch][j] = (short)l;
                }
            }
    }

    float bestd[16]; int bestk[16];
    #pragma unroll
    for (int i = 0; i < 16; ++i) { bestd[i] = FLT_MAX; bestk[i] = 0; }

    const int lr   = tid >> 1;
    const int half = tid & 1;

    for (int nt = 0; nt < KD / KT; ++nt) {
        __syncthreads();
        {
            const float* eg = emb + (size_t)(nt * KT + lr) * CD + half * 32;
            float s = 0.f;
            #pragma unroll
            for (int q = 0; q < 8; ++q) {
                float4 ev = *(const float4*)(eg + q * 4);
                float vv[4] = {ev.x, ev.y, ev.z, ev.w};
                ushort4 h4, m4, l4;
                unsigned short* hp = (unsigned short*)&h4;
                unsigned short* mp = (unsigned short*)&m4;
                unsigned short* lp = (unsigned short*)&l4;
                #pragma unroll
                for (int i = 0; i < 4; ++i) {
                    s = fmaf(vv[i], vv[i], s);
                    split3(vv[i], hp[i], mp[i], lp[i]);
                }
                int c0 = half * 32 + q * 4;
                *(ushort4*)&es_h[lr][c0] = h4;
                *(ushort4*)&es_m[lr][c0] = m4;
                *(ushort4*)&es_l[lr][c0] = l4;
            }
            esq_p[2 * lr + half] = s;
        }
        __syncthreads();

        #pragma unroll 2
        for (int ln = 0; ln < 8; ++ln) {
            const int krow = ln * 16 + n16;
            const unsigned short* ph = &es_h[krow][quad * 8];
            const unsigned short* pm = &es_m[krow][quad * 8];
            const unsigned short* pl = &es_l[krow][quad * 8];
            short8 bh0 = *(const short8*)ph,  bh1 = *(const short8*)(ph + 32);
            short8 bm0 = *(const short8*)pm,  bm1 = *(const short8*)(pm + 32);
            short8 bl0 = *(const short8*)pl,  bl1 = *(const short8*)(pl + 32);
            const float eq = esq_p[2 * krow] + esq_p[2 * krow + 1];
            const int   kv = nt * KT + ln * 16 + n16;

            floatx4 acc[4];
            #pragma unroll
            for (int mt = 0; mt < 4; ++mt) acc[mt] = (floatx4){0.f, 0.f, 0.f, 0.f};

            #define STEPF(AR, B0, B1)                                         \
                { _Pragma("unroll")                                           \
                  for (int mt = 0; mt < 4; ++mt) acc[mt] = MFMA16(AR[mt][0], B0, acc[mt]); \
                  _Pragma("unroll")                                           \
                  for (int mt = 0; mt < 4; ++mt) acc[mt] = MFMA16(AR[mt][1], B1, acc[mt]); }
            STEPF(al, bh0, bh1)
            STEPF(am, bm0, bm1)
            STEPF(ah, bl0, bl1)
            STEPF(am, bh0, bh1)
            STEPF(ah, bm0, bm1)
            STEPF(ah, bh0, bh1)
            #undef STEPF

            #pragma unroll
            for (int mt = 0; mt < 4; ++mt)
                #pragma unroll
                for (int r = 0; r < 4; ++r) {
                    float d = fmaf(-2.f, acc[mt][r], eq);
                    int idx = mt * 4 + r;
                    if (d < bestd[idx]) { bestd[idx] = d; bestk[idx] = kv; }
                }
        }
    }

    #pragma unroll
    for (int msk = 1; msk <= 8; msk <<= 1)
        #pragma unroll
        for (int i = 0; i < 16; ++i) {
            float od = __shfl_xor(bestd[i], msk, 64);
            int   ok = __shfl_xor(bestk[i], msk, 64);
            bool take = (od < bestd[i]) || (od == bestd[i] && ok < bestk[i]);
            if (take) { bestd[i] = od; bestk[i] = ok; }
        }
    if (n16 == 0) {
        #pragma unroll
        for (int mt = 0; mt < 4; ++mt)
            #pragma unroll
            for (int r = 0; r < 4; ++r)
                bk_s[wv * 64 + mt * 16 + quad * 4 + r] = bestk[mt * 4 + r];
    }
    __syncthreads();

    const size_t ob = (size_t)g0 * CD;
    for (int it = 0; it < 16; ++it) {
        float v[4]; int pp[4];
        #pragma unroll
        for (int j = 0; j < 4; ++j) {
            int p = (it * 4 + j) * 4 + wv;
            pp[j] = p;
            v[j]  = emb[bk_s[p] * CD + lane];
        }
        #pragma unroll
        for (int j = 0; j < 4; ++j)
            out[ob + (size_t)pp[j] * CD + lane] = v[j];
    }
}

extern "C" void kernel_launch(void* const* d_in, const int* in_sizes, int n_in,
                              void* d_out, int out_size, void* d_ws, size_t ws_size,
                              hipStream_t stream) {
    const float* x   = (const float*)d_in[0];   // 32*64*64*64
    const float* emb = (const float*)d_in[1];   // 512*64
    float* out = (float*)d_out;                 // 8388608 floats

    if (d_ws != nullptr && ws_size >= (size_t)WS_NEEDED) {
        unsigned short* bs = (unsigned short*)d_ws;     // 196608 B
        float* esq = (float*)((char*)d_ws + ESQ_OFF);   // 512 floats
        vq_prep32<<<16, 64, 0, stream>>>(emb, bs, esq);
        vq_mfma32_kernel<<<1024, 256, 0, stream>>>(x, bs, esq, emb, out);
    } else {
        vq_mfma_fb<<<512, 256, 0, stream>>>(x, emb, out);
    }
}

// Round 7
// 119.781 us; speedup vs baseline: 1.1149x; 1.1149x over previous
//
#include <hip/hip_runtime.h>
#include <float.h>

// VQ-VAE vector quantizer forward, MI355X — bf16 MFMA with exact 3-way split.
// x: [B=32, C=64, H=64, W=64] fp32; emb: [K=512, D=64] fp32.
// out flat (b, h*w, c): out[g*64 + c] = emb[argmin_k ||x_g - emb_k||^2][c].
//
// R14: fix the per-wave duty cycle. Corrected model (per-SIMD MFMA cost
// 19.4cy): R12's matrix pipe is ~50% busy; the 4 in-phase waves/SIMD each
// spend ~(120cy lgkm wait + 70cy argmin tail + barrier) serial per kt that
// siblings (same phase) can't cover. R13 (32x32, 1 acc chain) made it worse.
// R14 keeps R12's numerics BIT-IDENTICAL and restructures the schedule:
//  (1) frags of tile t+1 ds_read BEFORE tile t's MFMA cluster (lgkm wait
//      lands behind ~466cy of MFMA),
//  (2) argmin TAIL of tile t deferred until after tile t+1's cluster is
//      issued (VALU overlaps matrix drain; accA/accB ping-pong, static),
//  (3) 2-tile rounds on a 4-slot LDS ring (24KB): 16 barriers not 32,
//      global_load_lds staging unchanged, drains covered by ~930cy MFMA.
// 4 blocks/CU, ~125 VGPR, no setprio (lockstep regime, m190).
// Pre-committed: if dur >= 52us, next round ablates (asm-keepalive stubs),
// not optimizes.
//
// Verified layouts (m89/m91/m120): A[m=lane&15][k=quad*8+j],
// B[n=lane&15][k=quad*8+j], D col=lane&15, row=quad*4+reg.

typedef __attribute__((ext_vector_type(8))) short  short8;
typedef __attribute__((ext_vector_type(4))) float  floatx4;

#define HWD 4096
#define CD  64
#define KD  512
#define PT  128    // positions per block
#define KT  128    // fallback path: emb rows per nt
#define ESR 72     // fallback LDS row stride

// ws layout: bs = 32 kt-tiles x 3072 ushorts ([lvl][ch][lane][8], 16 codes
// per tile) = 196608 B; esq = 512 pre-summed |e|^2 floats at 196608.
#define KT_USH    3072
#define TILE_B    (KT_USH * 2)                            // 6144 B per tile
#define BS_BYTES  (32 * TILE_B)                           // 196608
#define ESQ_OFF   BS_BYTES
#define WS_NEEDED (ESQ_OFF + 512 * (int)sizeof(float))    // 198656

// round-to-nearest-even fp32 -> bf16 (bit-level; inputs are finite)
__device__ inline unsigned short bf16_rne(float v) {
    unsigned int u = __builtin_bit_cast(unsigned int, v);
    u += 0x7fffu + ((u >> 16) & 1u);
    return (unsigned short)(u >> 16);
}
__device__ inline float bf16_val(unsigned short h) {
    return __builtin_bit_cast(float, (unsigned int)h << 16);
}
// exact 3-way split: v = h + m + l + eps, |eps| <= 2^-27 |v|
__device__ inline void split3(float v, unsigned short& h, unsigned short& m,
                              unsigned short& l) {
    h = bf16_rne(v);
    float r1 = v - bf16_val(h);     // exact in fp32
    m = bf16_rne(r1);
    float r2 = r1 - bf16_val(m);    // exact in fp32
    l = bf16_rne(r2);
}

#define MFMA(A, B, C) __builtin_amdgcn_mfma_f32_16x16x32_bf16((A), (B), (C), 0, 0, 0)

// async global -> LDS, 16 B per lane; LDS dest = wave-uniform base + lane*16
__device__ inline void gload_lds16(const void* g, void* l) {
    __builtin_amdgcn_global_load_lds(
        (const __attribute__((address_space(1))) void*)g,
        (__attribute__((address_space(3))) void*)l, 16, 0, 0);
}

// ---- prep: split emb into B-fragment layout + pre-summed |e|^2 ----
// thread t (0..1023): k = t>>1, half = t&1. Same load order / fmaf chain /
// split3 as R7's staging; eq = half0_partial + half1_partial (same order)
// -> bit-identical distances.
__global__ void vq_prep(const float* __restrict__ emb,
                        unsigned short* __restrict__ bs,
                        float* __restrict__ esq) {
    const int t    = blockIdx.x * blockDim.x + threadIdx.x;  // 0..1023
    const int k    = t >> 1;
    const int half = t & 1;
    const int n16  = k & 15;
    const float* eg = emb + (size_t)k * CD + half * 32;
    // base of this (kt-tile, ch=half, n16) within bs, ushort units
    unsigned short* bb = bs + (size_t)(k >> 4) * KT_USH + half * 512 + n16 * 8;
    float s = 0.f;
    #pragma unroll
    for (int q = 0; q < 8; ++q) {
        float4 ev = *(const float4*)(eg + q * 4);
        float vv[4] = {ev.x, ev.y, ev.z, ev.w};
        #pragma unroll
        for (int i = 0; i < 4; ++i) {
            s = fmaf(vv[i], vv[i], s);
            unsigned short h, m, l;
            split3(vv[i], h, m, l);
            const int c    = half * 32 + q * 4 + i;   // 0..63
            const int quad = (c >> 3) & 3;
            const int j    = c & 7;
            const int off  = quad * 128 + j;          // (quad*16)*8 + j
            bb[off]        = h;                       // lvl 0 (frag lvl*2+ch)
            bb[1024 + off] = m;                       // lvl 1
            bb[2048 + off] = l;                       // lvl 2
        }
    }
    // lanes 2k, 2k+1 hold the two half-partials of code k
    float o = __shfl_xor(s, 1, 64);
    if (half == 0) esq[k] = s + o;    // == R7's esq_p[2k] + esq_p[2k+1]
}

// ---- main kernel: 4-slot LDS ring, frag prefetch, deferred argmin ----
__launch_bounds__(256, 4)
__global__ void vq_mfma_kernel(const float* __restrict__ x,
                               const unsigned short* __restrict__ bs,
                               const float* __restrict__ esq,
                               const float* __restrict__ emb,
                               float* __restrict__ out) {
    const int tid  = threadIdx.x;
    const int lane = tid & 63;
    const int wv   = __builtin_amdgcn_readfirstlane(tid >> 6);  // 0..3
    const int n16  = lane & 15;   // m for A, n for B, col for D
    const int quad = lane >> 4;   // k-quad for A/B, row-quad for D

    const int g0 = blockIdx.x << 7;   // 128 positions per block
    const int b  = g0 >> 12;          // 128 | 4096: no b straddle
    const int n0 = g0 & 4095;

    __shared__ unsigned short lds_b[4][KT_USH];   // 4 slots x 6144 B (ring)
    __shared__ int bk_s[PT];

    const char* bsb = (const char*)bs;
    char* lds0 = (char*)&lds_b[0][0];

    // staging split: wave wv covers chunk indices {wv, wv+4, wv+8} of the
    // 12 chunks (2 tiles x 6 frags x 1024 B) staged per round
    int st_t[3], st_c[3];
    #pragma unroll
    for (int s = 0; s < 3; ++s) {
        int cidx = wv + 4 * s;          // 0..11
        st_t[s] = (cidx < 6) ? 0 : 1;   // tile offset within the pair
        st_c[s] = (cidx < 6) ? cidx : cidx - 6;
    }

    // ---- stage tiles 0,1 first; DMA latency hides under split3 ----
    #pragma unroll
    for (int s = 0; s < 3; ++s)
        gload_lds16(bsb + (size_t)st_t[s] * TILE_B + st_c[s] * 1024 + lane * 16,
                    lds0 + st_t[s] * TILE_B + st_c[s] * 1024);

    // ---- A fragments: load x, split to 3 bf16 frags (held whole kernel) ----
    // pos = g0 + wv*32 + mt*16 + n16 ; k(c) = ch*32 + quad*8 + j
    short8 ah[2][2], am[2][2], al[2][2];
    {
        const float* xb = x + (size_t)b * (CD * HWD) + n0 + wv * 32 + n16;
        #pragma unroll
        for (int mt = 0; mt < 2; ++mt)
            #pragma unroll
            for (int ch = 0; ch < 2; ++ch) {
                #pragma unroll
                for (int j = 0; j < 8; ++j) {
                    float v = xb[(size_t)(ch * 32 + quad * 8 + j) * HWD + mt * 16];
                    unsigned short h, m, l;
                    split3(v, h, m, l);
                    ah[mt][ch][j] = (short)h;
                    am[mt][ch][j] = (short)m;
                    al[mt][ch][j] = (short)l;
                }
            }
    }

    float bestd[8]; int bestk[8];
    #pragma unroll
    for (int i = 0; i < 8; ++i) { bestd[i] = FLT_MAX; bestk[i] = 0; }

    __syncthreads();   // tiles 0,1 resident

    // 6-class small->large accumulation, 2 chains (mt); R12-identical order.
    // F[0],F[1]=e_h  F[2],F[3]=e_m  F[4],F[5]=e_l  (ch 0/1 each)
    #define CLUSTER(F, ACC)                                                   \
        { _Pragma("unroll")                                                   \
          for (int mt = 0; mt < 2; ++mt) ACC[mt] = MFMA(al[mt][0], F[0], ACC[mt]); \
          _Pragma("unroll")                                                   \
          for (int mt = 0; mt < 2; ++mt) ACC[mt] = MFMA(al[mt][1], F[1], ACC[mt]); \
          _Pragma("unroll")                                                   \
          for (int mt = 0; mt < 2; ++mt) ACC[mt] = MFMA(am[mt][0], F[2], ACC[mt]); \
          _Pragma("unroll")                                                   \
          for (int mt = 0; mt < 2; ++mt) ACC[mt] = MFMA(am[mt][1], F[3], ACC[mt]); \
          _Pragma("unroll")                                                   \
          for (int mt = 0; mt < 2; ++mt) ACC[mt] = MFMA(ah[mt][0], F[4], ACC[mt]); \
          _Pragma("unroll")                                                   \
          for (int mt = 0; mt < 2; ++mt) ACC[mt] = MFMA(ah[mt][1], F[5], ACC[mt]); \
          _Pragma("unroll")                                                   \
          for (int mt = 0; mt < 2; ++mt) ACC[mt] = MFMA(am[mt][0], F[0], ACC[mt]); \
          _Pragma("unroll")                                                   \
          for (int mt = 0; mt < 2; ++mt) ACC[mt] = MFMA(am[mt][1], F[1], ACC[mt]); \
          _Pragma("unroll")                                                   \
          for (int mt = 0; mt < 2; ++mt) ACC[mt] = MFMA(ah[mt][0], F[2], ACC[mt]); \
          _Pragma("unroll")                                                   \
          for (int mt = 0; mt < 2; ++mt) ACC[mt] = MFMA(ah[mt][1], F[3], ACC[mt]); \
          _Pragma("unroll")                                                   \
          for (int mt = 0; mt < 2; ++mt) ACC[mt] = MFMA(ah[mt][0], F[0], ACC[mt]); \
          _Pragma("unroll")                                                   \
          for (int mt = 0; mt < 2; ++mt) ACC[mt] = MFMA(ah[mt][1], F[1], ACC[mt]); }

    // distances + running argmin (k ascending: strict < keeps lowest k)
    #define TAIL(ACC, EQ, KV)                                                 \
        { _Pragma("unroll")                                                   \
          for (int mt = 0; mt < 2; ++mt)                                      \
              _Pragma("unroll")                                               \
              for (int r2 = 0; r2 < 4; ++r2) {                                \
                  float d = fmaf(-2.f, ACC[mt][r2], (EQ));                    \
                  int idx = mt * 4 + r2;                                      \
                  if (d < bestd[idx]) { bestd[idx] = d; bestk[idx] = (KV); }  \
              } }

    short8 f[6], g[6];
    floatx4 accA[2], accB[2];
    float eqBprev = 0.f;

    // ---- main loop: 16 rounds x 2 tiles; ring slot = tile & 3 ----
    #pragma unroll 1
    for (int r = 0; r < 16; ++r) {
        const int tA = 2 * r, tB = 2 * r + 1;

        // (a) f <- frags(tile tA) from slot tA&3 (staged round r-1)
        {
            const char* sb = lds0 + (tA & 3) * TILE_B;
            #pragma unroll
            for (int i = 0; i < 6; ++i)
                f[i] = *(const short8*)(sb + i * 1024 + lane * 16);
        }
        // (b) stage tiles tA+2, tB+2 into the slots read last round
        if (r < 15) {
            #pragma unroll
            for (int s = 0; s < 3; ++s) {
                const int tt = tA + 2 + st_t[s];
                gload_lds16(bsb + (size_t)tt * TILE_B + st_c[s] * 1024 + lane * 16,
                            lds0 + (tt & 3) * TILE_B + st_c[s] * 1024);
            }
        }
        const float eqa = esq[tA * 16 + n16];
        const float eqb = esq[tB * 16 + n16];
        // (c) g <- frags(tile tB) from slot tB&3 (staged round r-1)
        {
            const char* sb = lds0 + (tB & 3) * TILE_B;
            #pragma unroll
            for (int i = 0; i < 6; ++i)
                g[i] = *(const short8*)(sb + i * 1024 + lane * 16);
        }
        // (d) MFMA on f -> accA
        #pragma unroll
        for (int mt = 0; mt < 2; ++mt) accA[mt] = (floatx4){0.f, 0.f, 0.f, 0.f};
        CLUSTER(f, accA)
        // (e) deferred argmin for tile 2r-1 (acc done since last round)
        if (r > 0) TAIL(accB, eqBprev, (tA - 1) * 16 + n16)
        // (f) MFMA on g -> accB
        #pragma unroll
        for (int mt = 0; mt < 2; ++mt) accB[mt] = (floatx4){0.f, 0.f, 0.f, 0.f};
        CLUSTER(g, accB)
        // (g) argmin for tile tA (its chain drained under (e)+(f))
        TAIL(accA, eqa, tA * 16 + n16)
        eqBprev = eqb;
        // (h) barrier: drains this round's DMA (covered by ~930cy of MFMA);
        //     protects next round's slot overwrite
        __syncthreads();
    }
    // final deferred argmin: tile 31
    TAIL(accB, eqBprev, 31 * 16 + n16)
    #undef CLUSTER
    #undef TAIL

    // ---- cross-lane argmin over the 16 code-columns (lane bits 0..3) ----
    #pragma unroll
    for (int msk = 1; msk <= 8; msk <<= 1)
        #pragma unroll
        for (int i = 0; i < 8; ++i) {
            float od = __shfl_xor(bestd[i], msk, 64);
            int   ok = __shfl_xor(bestk[i], msk, 64);
            bool take = (od < bestd[i]) || (od == bestd[i] && ok < bestk[i]);
            if (take) { bestd[i] = od; bestk[i] = ok; }
        }
    // D row = quad*4 + r within tile -> pos = wv*32 + mt*16 + quad*4 + r
    if (n16 == 0) {
        #pragma unroll
        for (int mt = 0; mt < 2; ++mt)
            #pragma unroll
            for (int r = 0; r < 4; ++r)
                bk_s[wv * 32 + mt * 16 + quad * 4 + r] = bestk[mt * 4 + r];
    }
    __syncthreads();

    // ---- gather epilogue: wave-uniform rows, 256-B coalesced, batched ----
    const size_t ob = (size_t)g0 * CD;
    for (int it = 0; it < 8; ++it) {
        float v[4]; int pp[4];
        #pragma unroll
        for (int j = 0; j < 4; ++j) {
            int p = (it * 4 + j) * 4 + wv;
            pp[j] = p;
            v[j]  = emb[bk_s[p] * CD + lane];   // L2-hot fp32 row
        }
        #pragma unroll
        for (int j = 0; j < 4; ++j)
            out[ob + (size_t)pp[j] * CD + lane] = v[j];
    }
}

// ---- fallback (no workspace): verbatim R7 kernel, 123.7 us known-good ----
__launch_bounds__(256, 2)
__global__ void vq_mfma_fb(const float* __restrict__ x,
                           const float* __restrict__ emb,
                           float* __restrict__ out) {
    const int tid  = threadIdx.x;
    const int lane = tid & 63;
    const int wv   = __builtin_amdgcn_readfirstlane(tid >> 6);  // 0..3
    const int n16  = lane & 15;
    const int quad = lane >> 4;

    const int g0 = blockIdx.x << 8;
    const int b  = g0 >> 12;
    const int n0 = g0 & 4095;

    __shared__ unsigned short es_h[KT][ESR];
    __shared__ unsigned short es_m[KT][ESR];
    __shared__ unsigned short es_l[KT][ESR];
    __shared__ float esq_p[2 * KT];
    __shared__ int   bk_s[256];

    short8 ah[4][2], am[4][2], al[4][2];
    {
        const float* xb = x + (size_t)b * (CD * HWD) + n0 + wv * 64 + n16;
        #pragma unroll
        for (int mt = 0; mt < 4; ++mt)
            #pragma unroll
            for (int ch = 0; ch < 2; ++ch) {
                #pragma unroll
                for (int j = 0; j < 8; ++j) {
                    float v = xb[(size_t)(ch * 32 + quad * 8 + j) * HWD + mt * 16];
                    unsigned short h, m, l;
                    split3(v, h, m, l);
                    ah[mt][ch][j] = (short)h;
                    am[mt][ch][j] = (short)m;
                    al[mt][ch][j] = (short)l;
                }
            }
    }

    float bestd[16]; int bestk[16];
    #pragma unroll
    for (int i = 0; i < 16; ++i) { bestd[i] = FLT_MAX; bestk[i] = 0; }

    const int lr   = tid >> 1;
    const int half = tid & 1;

    for (int nt = 0; nt < KD / KT; ++nt) {
        __syncthreads();
        {
            const float* eg = emb + (size_t)(nt * KT + lr) * CD + half * 32;
            float s = 0.f;
            #pragma unroll
            for (int q = 0; q < 8; ++q) {
                float4 ev = *(const float4*)(eg + q * 4);
                float vv[4] = {ev.x, ev.y, ev.z, ev.w};
                ushort4 h4, m4, l4;
                unsigned short* hp = (unsigned short*)&h4;
                unsigned short* mp = (unsigned short*)&m4;
                unsigned short* lp = (unsigned short*)&l4;
                #pragma unroll
                for (int i = 0; i < 4; ++i) {
                    s = fmaf(vv[i], vv[i], s);
                    split3(vv[i], hp[i], mp[i], lp[i]);
                }
                int c0 = half * 32 + q * 4;
                *(ushort4*)&es_h[lr][c0] = h4;
                *(ushort4*)&es_m[lr][c0] = m4;
                *(ushort4*)&es_l[lr][c0] = l4;
            }
            esq_p[2 * lr + half] = s;
        }
        __syncthreads();

        #pragma unroll 2
        for (int ln = 0; ln < 8; ++ln) {
            const int krow = ln * 16 + n16;
            const unsigned short* ph = &es_h[krow][quad * 8];
            const unsigned short* pm = &es_m[krow][quad * 8];
            const unsigned short* pl = &es_l[krow][quad * 8];
            short8 bh0 = *(const short8*)ph,  bh1 = *(const short8*)(ph + 32);
            short8 bm0 = *(const short8*)pm,  bm1 = *(const short8*)(pm + 32);
            short8 bl0 = *(const short8*)pl,  bl1 = *(const short8*)(pl + 32);
            const float eq = esq_p[2 * krow] + esq_p[2 * krow + 1];
            const int   kv = nt * KT + ln * 16 + n16;

            floatx4 acc[4];
            #pragma unroll
            for (int mt = 0; mt < 4; ++mt) acc[mt] = (floatx4){0.f, 0.f, 0.f, 0.f};

            #define STEPF(AR, B0, B1)                                         \
                { _Pragma("unroll")                                           \
                  for (int mt = 0; mt < 4; ++mt) acc[mt] = MFMA(AR[mt][0], B0, acc[mt]); \
                  _Pragma("unroll")                                           \
                  for (int mt = 0; mt < 4; ++mt) acc[mt] = MFMA(AR[mt][1], B1, acc[mt]); }
            STEPF(al, bh0, bh1)
            STEPF(am, bm0, bm1)
            STEPF(ah, bl0, bl1)
            STEPF(am, bh0, bh1)
            STEPF(ah, bm0, bm1)
            STEPF(ah, bh0, bh1)
            #undef STEPF

            #pragma unroll
            for (int mt = 0; mt < 4; ++mt)
                #pragma unroll
                for (int r = 0; r < 4; ++r) {
                    float d = fmaf(-2.f, acc[mt][r], eq);
                    int idx = mt * 4 + r;
                    if (d < bestd[idx]) { bestd[idx] = d; bestk[idx] = kv; }
                }
        }
    }

    #pragma unroll
    for (int msk = 1; msk <= 8; msk <<= 1)
        #pragma unroll
        for (int i = 0; i < 16; ++i) {
            float od = __shfl_xor(bestd[i], msk, 64);
            int   ok = __shfl_xor(bestk[i], msk, 64);
            bool take = (od < bestd[i]) || (od == bestd[i] && ok < bestk[i]);
            if (take) { bestd[i] = od; bestk[i] = ok; }
        }
    if (n16 == 0) {
        #pragma unroll
        for (int mt = 0; mt < 4; ++mt)
            #pragma unroll
            for (int r = 0; r < 4; ++r)
                bk_s[wv * 64 + mt * 16 + quad * 4 + r] = bestk[mt * 4 + r];
    }
    __syncthreads();

    const size_t ob = (size_t)g0 * CD;
    for (int it = 0; it < 16; ++it) {
        float v[4]; int pp[4];
        #pragma unroll
        for (int j = 0; j < 4; ++j) {
            int p = (it * 4 + j) * 4 + wv;
            pp[j] = p;
            v[j]  = emb[bk_s[p] * CD + lane];
        }
        #pragma unroll
        for (int j = 0; j < 4; ++j)
            out[ob + (size_t)pp[j] * CD + lane] = v[j];
    }
}

extern "C" void kernel_launch(void* const* d_in, const int* in_sizes, int n_in,
                              void* d_out, int out_size, void* d_ws, size_t ws_size,
                              hipStream_t stream) {
    const float* x   = (const float*)d_in[0];   // 32*64*64*64
    const float* emb = (const float*)d_in[1];   // 512*64
    float* out = (float*)d_out;                 // 8388608 floats

    if (d_ws != nullptr && ws_size >= (size_t)WS_NEEDED) {
        unsigned short* bs = (unsigned short*)d_ws;     // 196608 B
        float* esq = (float*)((char*)d_ws + ESQ_OFF);   // 512 floats
        vq_prep<<<16, 64, 0, stream>>>(emb, bs, esq);
        vq_mfma_kernel<<<1024, 256, 0, stream>>>(x, bs, esq, emb, out);
    } else {
        vq_mfma_fb<<<512, 256, 0, stream>>>(x, emb, out);
    }
}